// Round 7
// baseline (260.437 us; speedup 1.0000x reference)
//
#include <hip/hip_runtime.h>

#define F 128

typedef __attribute__((ext_vector_type(8))) short short8v;   // 8 bf16 (4 VGPR)
typedef __attribute__((ext_vector_type(4))) float f32x4;     // MFMA accumulator

__device__ __forceinline__ unsigned short f2bf(float f) {
    unsigned int u = __builtin_bit_cast(unsigned int, f);
    unsigned int r = (u + 0x7fffu + ((u >> 16) & 1u)) >> 16;
    return (unsigned short)r;
}
__device__ __forceinline__ float bf2f(unsigned int b16) {
    unsigned int u = b16 << 16;
    return __builtin_bit_cast(float, u);
}

__device__ __forceinline__ int load_src(const int* ei, int is64, int E, int e) {
    return is64 ? ei[2 * e] : ei[e];
}
__device__ __forceinline__ int load_dst(const int* ei, int is64, int E, int e) {
    return is64 ? ei[2 * (E + e)] : ei[E + e];
}

// ---------------- prep: zero deg + dtype probe + x->bf16 + 3x W-pack ----------------
__global__ void prep(const int* __restrict__ ei, int* __restrict__ flag,
                     int* __restrict__ deg, int N,
                     const float* __restrict__ x, unsigned short* __restrict__ xb,
                     int ndegb, int nxb,
                     const float* __restrict__ Wl0, const float* __restrict__ Wr0,
                     const float* __restrict__ Wl1, const float* __restrict__ Wr1,
                     const float* __restrict__ Wl2, const float* __restrict__ Wr2,
                     unsigned short* __restrict__ Wp) {
    int b = blockIdx.x;
    if (b < ndegb) {
        int i = b * 256 + threadIdx.x;
        if (i < N) deg[i] = 0;
        if (b == 0) {
            __shared__ int any_nonzero;
            if (threadIdx.x == 0) any_nonzero = 0;
            __syncthreads();
            // int64 (LE, values < 2^31) => every odd 32-bit word is 0.
            int v = ei[2 * threadIdx.x + 1];
            if (v != 0) atomicOr(&any_nonzero, 1);
            __syncthreads();
            if (threadIdx.x == 0) *flag = (any_nonzero == 0) ? 1 : 0;  // 1 => int64
        }
        return;
    }
    if (b < ndegb + nxb) {
        int i = (b - ndegb) * 256 + threadIdx.x;
        float4 v = *(const float4*)(x + (size_t)i * 4);
        ushort4 o;
        o.x = f2bf(v.x); o.y = f2bf(v.y); o.z = f2bf(v.z); o.w = f2bf(v.w);
        *(ushort4*)(xb + (size_t)i * 4) = o;
        return;
    }
    // W pack: Wp[L][kt][nt][lane][i] = W[kt*32 + (lane>>4)*8 + i][nt*16 + (lane&15)]
    int t = (b - ndegb - nxb) * 256 + threadIdx.x;  // 0..12287
    int L = t >> 12;
    int tt = t & 4095;
    const float* Wl = (L == 0) ? Wl0 : (L == 1) ? Wl1 : Wl2;
    const float* Wr = (L == 0) ? Wr0 : (L == 1) ? Wr1 : Wr2;
    int lane = tt & 63;
    int nt = (tt >> 6) & 7;
    int kt = (tt >> 9) & 7;
    int c = nt * 16 + (lane & 15);
    int kbase = kt * 32 + ((lane >> 4) << 3);
    unsigned short o[8];
#pragma unroll
    for (int i = 0; i < 8; ++i) {
        int k = kbase + i;
        float v = (k < 128) ? Wl[k * F + c] : Wr[(k - 128) * F + c];
        o[i] = f2bf(v);
    }
    *(uint4*)(Wp + ((size_t)L * 32768) + (size_t)tt * 8) = *(const uint4*)o;
}

// ---------------- degree histogram + per-edge rank ----------------
__global__ void count_rank(const int* __restrict__ ei, const int* __restrict__ flag,
                           int* __restrict__ deg, int* __restrict__ rank, int E) {
    int e = blockIdx.x * blockDim.x + threadIdx.x;
    if (e >= E) return;
    int is64 = *flag;
    int d = load_dst(ei, is64, E, e);
    rank[e] = atomicAdd(&deg[d], 1);
}

// ---------------- local scan: chunks of 1024 -> chunk-local prefix + partials ----------------
__global__ __launch_bounds__(1024) void scan_local(const int* __restrict__ deg,
                                                   int* __restrict__ rs,
                                                   int* __restrict__ partials, int N) {
    __shared__ int wsum[16];
    const int tid = threadIdx.x;
    const int lane = tid & 63, wid = tid >> 6;
    int i = blockIdx.x * 1024 + tid;
    int v = (i < N) ? deg[i] : 0;
    int incl = v;
#pragma unroll
    for (int d = 1; d < 64; d <<= 1) {
        int t = __shfl_up(incl, d);
        if (lane >= d) incl += t;
    }
    if (lane == 63) wsum[wid] = incl;
    __syncthreads();
    if (tid == 0) {
        int acc = 0;
#pragma unroll
        for (int w = 0; w < 16; ++w) { int t = wsum[w]; wsum[w] = acc; acc += t; }
        partials[blockIdx.x] = acc;
    }
    __syncthreads();
    if (i < N) rs[i] = wsum[wid] + (incl - v);  // chunk-local exclusive prefix
}

// ---------------- CSR fill (atomic-free; chunk offsets derived in-block) ----------------
// requires nch <= 64
__global__ void fill_adj(const int* __restrict__ ei, const int* __restrict__ flag,
                         const int* __restrict__ rs, const int* __restrict__ partials,
                         int nch, const int* __restrict__ rank,
                         int* __restrict__ adj, int E) {
    __shared__ int sCoff[64];
    if (threadIdx.x < 64) {  // wave 0 scans chunk totals
        int t = threadIdx.x;
        int v = (t < nch) ? partials[t] : 0;
        int incl = v;
#pragma unroll
        for (int d = 1; d < 64; d <<= 1) {
            int s = __shfl_up(incl, d);
            if (t >= d) incl += s;
        }
        sCoff[t] = incl - v;  // exclusive
    }
    __syncthreads();
    int e = blockIdx.x * blockDim.x + threadIdx.x;
    if (e >= E) return;
    int is64 = *flag;
    int s = load_src(ei, is64, E, e);
    int d = load_dst(ei, is64, E, e);
    adj[rs[d] + sCoff[d >> 10] + rank[e]] = s;
}

// ---------------- fused layer: gather-mean into LDS, then MFMA ----------------
// 512 threads = 8 waves; block owns 128 rows (wave w: rows row0+w*16 .. +15).
// Phase 1: each wave gathers its 16 nodes (quarters q over edges, 16B/lane feats).
// Phase 2: A-frags (agg half) from LDS, (x half) from global; B from global Wpack.
#define AGG_PAD 136  // 128 + 8 shorts: row stride 272B, balanced banks for b128 reads
__global__ __launch_bounds__(512, 4) void sage_fused(
    const unsigned short* __restrict__ xb, const int* __restrict__ adj,
    const int* __restrict__ rs, const int* __restrict__ partials, int nch,
    const int* __restrict__ deg,
    const unsigned short* __restrict__ Wpack, const float* __restrict__ bl,
    unsigned short* __restrict__ outb, float* __restrict__ outf,
    int N, int final_layer) {
    __shared__ int sCoff[64];
    __shared__ unsigned short sAgg[128][AGG_PAD];  // 34 KB

    const int wid = threadIdx.x >> 6;
    const int lane = threadIdx.x & 63;
    const int row0 = blockIdx.x * 128;

    if (wid == 0) {  // wave 0 scans chunk totals
        int t = lane;
        int v = (t < nch) ? partials[t] : 0;
        int incl = v;
#pragma unroll
        for (int d = 1; d < 64; d <<= 1) {
            int s = __shfl_up(incl, d);
            if (t >= d) incl += s;
        }
        sCoff[t] = incl - v;
    }
    __syncthreads();

    // ---- phase 1: gather 16 nodes per wave ----
    const int q = lane >> 4, l4 = lane & 15;
    const unsigned short* xbase = xb + l4 * 8;
    for (int r = 0; r < 16; ++r) {
        const int lr = wid * 16 + r;
        const int n = row0 + lr;
        if (n >= N) break;
        const int start = rs[n] + sCoff[n >> 10];
        const int d = deg[n];
        float a0 = 0.f, a1 = 0.f, a2 = 0.f, a3 = 0.f;
        float a4 = 0.f, a5 = 0.f, a6 = 0.f, a7 = 0.f;
        int i = q;
        for (; i + 12 < d; i += 16) {
            int s0 = adj[start + i];
            int s1 = adj[start + i + 4];
            int s2 = adj[start + i + 8];
            int s3 = adj[start + i + 12];
            uint4 v0 = *(const uint4*)(xbase + (size_t)s0 * F);
            uint4 v1 = *(const uint4*)(xbase + (size_t)s1 * F);
            uint4 v2 = *(const uint4*)(xbase + (size_t)s2 * F);
            uint4 v3 = *(const uint4*)(xbase + (size_t)s3 * F);
            a0 += bf2f(v0.x & 0xffff) + bf2f(v1.x & 0xffff) + bf2f(v2.x & 0xffff) + bf2f(v3.x & 0xffff);
            a1 += bf2f(v0.x >> 16) + bf2f(v1.x >> 16) + bf2f(v2.x >> 16) + bf2f(v3.x >> 16);
            a2 += bf2f(v0.y & 0xffff) + bf2f(v1.y & 0xffff) + bf2f(v2.y & 0xffff) + bf2f(v3.y & 0xffff);
            a3 += bf2f(v0.y >> 16) + bf2f(v1.y >> 16) + bf2f(v2.y >> 16) + bf2f(v3.y >> 16);
            a4 += bf2f(v0.z & 0xffff) + bf2f(v1.z & 0xffff) + bf2f(v2.z & 0xffff) + bf2f(v3.z & 0xffff);
            a5 += bf2f(v0.z >> 16) + bf2f(v1.z >> 16) + bf2f(v2.z >> 16) + bf2f(v3.z >> 16);
            a6 += bf2f(v0.w & 0xffff) + bf2f(v1.w & 0xffff) + bf2f(v2.w & 0xffff) + bf2f(v3.w & 0xffff);
            a7 += bf2f(v0.w >> 16) + bf2f(v1.w >> 16) + bf2f(v2.w >> 16) + bf2f(v3.w >> 16);
        }
        for (; i < d; i += 4) {
            int s = adj[start + i];
            uint4 v = *(const uint4*)(xbase + (size_t)s * F);
            a0 += bf2f(v.x & 0xffff);
            a1 += bf2f(v.x >> 16);
            a2 += bf2f(v.y & 0xffff);
            a3 += bf2f(v.y >> 16);
            a4 += bf2f(v.z & 0xffff);
            a5 += bf2f(v.z >> 16);
            a6 += bf2f(v.w & 0xffff);
            a7 += bf2f(v.w >> 16);
        }
        a0 += __shfl_xor(a0, 16); a0 += __shfl_xor(a0, 32);
        a1 += __shfl_xor(a1, 16); a1 += __shfl_xor(a1, 32);
        a2 += __shfl_xor(a2, 16); a2 += __shfl_xor(a2, 32);
        a3 += __shfl_xor(a3, 16); a3 += __shfl_xor(a3, 32);
        a4 += __shfl_xor(a4, 16); a4 += __shfl_xor(a4, 32);
        a5 += __shfl_xor(a5, 16); a5 += __shfl_xor(a5, 32);
        a6 += __shfl_xor(a6, 16); a6 += __shfl_xor(a6, 32);
        a7 += __shfl_xor(a7, 16); a7 += __shfl_xor(a7, 32);
        if (q == 0) {
            float inv = 1.0f / fmaxf((float)d, 1.0f);
            uint4 o;
            o.x = ((unsigned int)f2bf(a1 * inv) << 16) | f2bf(a0 * inv);
            o.y = ((unsigned int)f2bf(a3 * inv) << 16) | f2bf(a2 * inv);
            o.z = ((unsigned int)f2bf(a5 * inv) << 16) | f2bf(a4 * inv);
            o.w = ((unsigned int)f2bf(a7 * inv) << 16) | f2bf(a6 * inv);
            *(uint4*)&sAgg[lr][l4 * 8] = o;
        }
    }
    __syncthreads();

    // ---- phase 2: MFMA (16 rows x 128 cols per wave, K=256) ----
    const int row0w = row0 + wid * 16;
    if (row0w >= N) return;

    const int lrA = wid * 16 + (lane & 15);
    const int kidx = (lane >> 4) << 3;  // 0,8,16,24
    int rX = row0w + (lane & 15);
    if (rX >= N) rX = N - 1;  // clamp: loads valid, results unstored
    const unsigned short* arow_x = xb + (size_t)rX * F + kidx;

    f32x4 acc[8];
#pragma unroll
    for (int nt = 0; nt < 8; ++nt) acc[nt] = (f32x4){0.f, 0.f, 0.f, 0.f};

#pragma unroll
    for (int kt = 0; kt < 8; ++kt) {
        short8v a;
        if (kt < 4) a = *(const short8v*)&sAgg[lrA][kt * 32 + kidx];
        else        a = *(const short8v*)(arow_x + (kt - 4) * 32);
#pragma unroll
        for (int nt = 0; nt < 8; ++nt) {
            short8v b = *(const short8v*)(Wpack + ((size_t)(kt * 8 + nt) * 64 + lane) * 8);
            acc[nt] = __builtin_amdgcn_mfma_f32_16x16x32_bf16(a, b, acc[nt], 0, 0, 0);
        }
    }

    // C/D layout: col = lane&15, row = (lane>>4)*4 + reg   [m89-verified]
    const int c0 = lane & 15;
    const int r0 = row0w + ((lane >> 4) << 2);
#pragma unroll
    for (int nt = 0; nt < 8; ++nt) {
        const int col = nt * 16 + c0;
        const float b = bl[col];
#pragma unroll
        for (int reg = 0; reg < 4; ++reg) {
            const int r = r0 + reg;
            if (r < N) {
                float v = acc[nt][reg] + b;
                if (!final_layer) {
                    v = fmaxf(v, 0.f);
                    outb[(size_t)r * F + col] = f2bf(v);
                } else {
                    outf[(size_t)r * F + col] = v;
                }
            }
        }
    }
}

extern "C" void kernel_launch(void* const* d_in, const int* in_sizes, int n_in,
                              void* d_out, int out_size, void* d_ws, size_t ws_size,
                              hipStream_t stream) {
    const float* x = (const float*)d_in[0];
    const int* ei = (const int*)d_in[1];
    const int E = in_sizes[1] / 2;
    const int N = in_sizes[0] / F;
    const int NCH = (N + 1023) / 1024;  // must be <= 64

    const float* Wl[3] = {(const float*)d_in[2], (const float*)d_in[5], (const float*)d_in[8]};
    const float* bl[3] = {(const float*)d_in[3], (const float*)d_in[6], (const float*)d_in[9]};
    const float* Wr[3] = {(const float*)d_in[4], (const float*)d_in[7], (const float*)d_in[10]};
    float* out = (float*)d_out;

    char* ws = (char*)d_ws;
    size_t off = 0;
    auto alloc = [&](size_t bytes) {
        size_t o = off;
        off = (off + bytes + 255) & ~(size_t)255;
        return o;
    };
    int* flag = (int*)(ws + alloc(4));
    int* deg = (int*)(ws + alloc((size_t)N * 4));
    int* rs = (int*)(ws + alloc((size_t)N * 4));
    int* partials = (int*)(ws + alloc(64 * 4));
    int* rank = (int*)(ws + alloc((size_t)E * 4));
    int* adj = (int*)(ws + alloc((size_t)E * 4));
    unsigned short* xb = (unsigned short*)(ws + alloc((size_t)N * F * 2));
    unsigned short* h1b = (unsigned short*)(ws + alloc((size_t)N * F * 2));
    unsigned short* h2b = (unsigned short*)(ws + alloc((size_t)N * F * 2));
    unsigned short* Wp = (unsigned short*)(ws + alloc((size_t)3 * 4096 * 8 * 2));

    // ---- prep: deg zero + flag + x->bf16 + W pack ----
    int ndegb = (N + 255) / 256;
    int nxb = (N * F / 4 + 255) / 256;
    prep<<<ndegb + nxb + 48, 256, 0, stream>>>(ei, flag, deg, N, x, xb, ndegb, nxb,
                                               Wl[0], Wr[0], Wl[1], Wr[1], Wl[2], Wr[2], Wp);

    // ---- CSR build ----
    count_rank<<<(E + 255) / 256, 256, 0, stream>>>(ei, flag, deg, rank, E);
    scan_local<<<NCH, 1024, 0, stream>>>(deg, rs, partials, N);
    fill_adj<<<(E + 255) / 256, 256, 0, stream>>>(ei, flag, rs, partials, NCH, rank, adj, E);

    // ---- fused layers ----
    const unsigned short* cur = xb;
    unsigned short* hb[3] = {h1b, h2b, nullptr};
    int nblocks = (N + 127) / 128;
    for (int layer = 0; layer < 3; ++layer) {
        sage_fused<<<nblocks, 512, 0, stream>>>(cur, adj, rs, partials, NCH, deg,
                                                Wp + (size_t)layer * 32768, bl[layer],
                                                hb[layer], out, N, layer == 2);
        cur = hb[layer];
    }
}

// Round 9
// 191.210 us; speedup vs baseline: 1.3620x; 1.3620x over previous
//
#include <hip/hip_runtime.h>

#define F 128

typedef __attribute__((ext_vector_type(8))) short short8v;   // 8 bf16 (4 VGPR)
typedef __attribute__((ext_vector_type(4))) float f32x4;     // MFMA accumulator

__device__ __forceinline__ unsigned short f2bf(float f) {
    unsigned int u = __builtin_bit_cast(unsigned int, f);
    unsigned int r = (u + 0x7fffu + ((u >> 16) & 1u)) >> 16;
    return (unsigned short)r;
}
__device__ __forceinline__ float bf2f(unsigned int b16) {
    unsigned int u = b16 << 16;
    return __builtin_bit_cast(float, u);
}

__device__ __forceinline__ int load_src(const int* ei, int is64, int E, int e) {
    return is64 ? ei[2 * e] : ei[e];
}
__device__ __forceinline__ int load_dst(const int* ei, int is64, int E, int e) {
    return is64 ? ei[2 * (E + e)] : ei[E + e];
}

// ---------------- prep: zero deg + dtype probe + x->bf16 + 3x W-pack ----------------
__global__ void prep(const int* __restrict__ ei, int* __restrict__ flag,
                     int* __restrict__ deg, int N,
                     const float* __restrict__ x, unsigned short* __restrict__ xb,
                     int ndegb, int nxb,
                     const float* __restrict__ Wl0, const float* __restrict__ Wr0,
                     const float* __restrict__ Wl1, const float* __restrict__ Wr1,
                     const float* __restrict__ Wl2, const float* __restrict__ Wr2,
                     unsigned short* __restrict__ Wp) {
    int b = blockIdx.x;
    if (b < ndegb) {
        int i = b * 256 + threadIdx.x;
        if (i < N) deg[i] = 0;
        if (b == 0) {
            __shared__ int any_nonzero;
            if (threadIdx.x == 0) any_nonzero = 0;
            __syncthreads();
            // int64 (LE, values < 2^31) => every odd 32-bit word is 0.
            int v = ei[2 * threadIdx.x + 1];
            if (v != 0) atomicOr(&any_nonzero, 1);
            __syncthreads();
            if (threadIdx.x == 0) *flag = (any_nonzero == 0) ? 1 : 0;  // 1 => int64
        }
        return;
    }
    if (b < ndegb + nxb) {
        int i = (b - ndegb) * 256 + threadIdx.x;
        float4 v = *(const float4*)(x + (size_t)i * 4);
        ushort4 o;
        o.x = f2bf(v.x); o.y = f2bf(v.y); o.z = f2bf(v.z); o.w = f2bf(v.w);
        *(ushort4*)(xb + (size_t)i * 4) = o;
        return;
    }
    // W pack: Wp[L][kt][nt][lane][i] = W[kt*32 + (lane>>4)*8 + i][nt*16 + (lane&15)]
    int t = (b - ndegb - nxb) * 256 + threadIdx.x;  // 0..12287
    int L = t >> 12;
    int tt = t & 4095;
    const float* Wl = (L == 0) ? Wl0 : (L == 1) ? Wl1 : Wl2;
    const float* Wr = (L == 0) ? Wr0 : (L == 1) ? Wr1 : Wr2;
    int lane = tt & 63;
    int nt = (tt >> 6) & 7;
    int kt = (tt >> 9) & 7;
    int c = nt * 16 + (lane & 15);
    int kbase = kt * 32 + ((lane >> 4) << 3);
    unsigned short o[8];
#pragma unroll
    for (int i = 0; i < 8; ++i) {
        int k = kbase + i;
        float v = (k < 128) ? Wl[k * F + c] : Wr[(k - 128) * F + c];
        o[i] = f2bf(v);
    }
    *(uint4*)(Wp + ((size_t)L * 32768) + (size_t)tt * 8) = *(const uint4*)o;
}

// ---------------- degree histogram + per-edge rank ----------------
__global__ void count_rank(const int* __restrict__ ei, const int* __restrict__ flag,
                           int* __restrict__ deg, int* __restrict__ rank, int E) {
    int e = blockIdx.x * blockDim.x + threadIdx.x;
    if (e >= E) return;
    int is64 = *flag;
    int d = load_dst(ei, is64, E, e);
    rank[e] = atomicAdd(&deg[d], 1);
}

// ---------------- local scan: chunks of 1024 -> chunk-local prefix + partials ----------------
__global__ __launch_bounds__(1024) void scan_local(const int* __restrict__ deg,
                                                   int* __restrict__ rs,
                                                   int* __restrict__ partials, int N) {
    __shared__ int wsum[16];
    const int tid = threadIdx.x;
    const int lane = tid & 63, wid = tid >> 6;
    int i = blockIdx.x * 1024 + tid;
    int v = (i < N) ? deg[i] : 0;
    int incl = v;
#pragma unroll
    for (int d = 1; d < 64; d <<= 1) {
        int t = __shfl_up(incl, d);
        if (lane >= d) incl += t;
    }
    if (lane == 63) wsum[wid] = incl;
    __syncthreads();
    if (tid == 0) {
        int acc = 0;
#pragma unroll
        for (int w = 0; w < 16; ++w) { int t = wsum[w]; wsum[w] = acc; acc += t; }
        partials[blockIdx.x] = acc;
    }
    __syncthreads();
    if (i < N) rs[i] = wsum[wid] + (incl - v);  // chunk-local exclusive prefix
}

// scan the <=64 chunk totals with one wave -> chunk offsets
__global__ void scan_part(const int* __restrict__ partials, int* __restrict__ coff,
                          int nch) {
    int tid = threadIdx.x;
    int v = (tid < nch) ? partials[tid] : 0;
    int incl = v;
#pragma unroll
    for (int d = 1; d < 64; d <<= 1) {
        int t = __shfl_up(incl, d);
        if (tid >= d) incl += t;
    }
    coff[tid] = incl - v;  // exclusive
}

// ---------------- CSR fill (atomic-free) ----------------
__global__ void fill_adj(const int* __restrict__ ei, const int* __restrict__ flag,
                         const int* __restrict__ rs, const int* __restrict__ coff,
                         const int* __restrict__ rank, int* __restrict__ adj, int E) {
    int e = blockIdx.x * blockDim.x + threadIdx.x;
    if (e >= E) return;
    int is64 = *flag;
    int s = load_src(ei, is64, E, e);
    int d = load_dst(ei, is64, E, e);
    adj[rs[d] + coff[d >> 10] + rank[e]] = s;
}

// ---------------- gather-mean: 4 edges per quarter-iteration, 16B/lane ----------------
// one wave per node; quarter q=lane>>4 handles edges q, q+4, q+8, ...
// lane loads uint4 = 8 bf16 feats at offset (lane&15)*8; unroll 4 (4 loads in flight)
__global__ __launch_bounds__(256) void gather_mean(
    const unsigned short* __restrict__ xb, const int* __restrict__ adj,
    const int* __restrict__ rs, const int* __restrict__ coff,
    const int* __restrict__ deg, unsigned short* __restrict__ aggb, int N) {
    int n = (blockIdx.x * blockDim.x + threadIdx.x) >> 6;
    if (n >= N) return;
    const int lane = threadIdx.x & 63;
    const int q = lane >> 4, l4 = lane & 15;
    const int start = rs[n] + coff[n >> 10];
    const int d = deg[n];
    const unsigned short* xbase = xb + l4 * 8;
    float a0 = 0.f, a1 = 0.f, a2 = 0.f, a3 = 0.f;
    float a4 = 0.f, a5 = 0.f, a6 = 0.f, a7 = 0.f;
    int i = q;
    for (; i + 12 < d; i += 16) {
        int s0 = adj[start + i];
        int s1 = adj[start + i + 4];
        int s2 = adj[start + i + 8];
        int s3 = adj[start + i + 12];
        uint4 v0 = *(const uint4*)(xbase + (size_t)s0 * F);
        uint4 v1 = *(const uint4*)(xbase + (size_t)s1 * F);
        uint4 v2 = *(const uint4*)(xbase + (size_t)s2 * F);
        uint4 v3 = *(const uint4*)(xbase + (size_t)s3 * F);
        a0 += bf2f(v0.x & 0xffff) + bf2f(v1.x & 0xffff) + bf2f(v2.x & 0xffff) + bf2f(v3.x & 0xffff);
        a1 += bf2f(v0.x >> 16) + bf2f(v1.x >> 16) + bf2f(v2.x >> 16) + bf2f(v3.x >> 16);
        a2 += bf2f(v0.y & 0xffff) + bf2f(v1.y & 0xffff) + bf2f(v2.y & 0xffff) + bf2f(v3.y & 0xffff);
        a3 += bf2f(v0.y >> 16) + bf2f(v1.y >> 16) + bf2f(v2.y >> 16) + bf2f(v3.y >> 16);
        a4 += bf2f(v0.z & 0xffff) + bf2f(v1.z & 0xffff) + bf2f(v2.z & 0xffff) + bf2f(v3.z & 0xffff);
        a5 += bf2f(v0.z >> 16) + bf2f(v1.z >> 16) + bf2f(v2.z >> 16) + bf2f(v3.z >> 16);
        a6 += bf2f(v0.w & 0xffff) + bf2f(v1.w & 0xffff) + bf2f(v2.w & 0xffff) + bf2f(v3.w & 0xffff);
        a7 += bf2f(v0.w >> 16) + bf2f(v1.w >> 16) + bf2f(v2.w >> 16) + bf2f(v3.w >> 16);
    }
    for (; i < d; i += 4) {
        int s = adj[start + i];
        uint4 v = *(const uint4*)(xbase + (size_t)s * F);
        a0 += bf2f(v.x & 0xffff);
        a1 += bf2f(v.x >> 16);
        a2 += bf2f(v.y & 0xffff);
        a3 += bf2f(v.y >> 16);
        a4 += bf2f(v.z & 0xffff);
        a5 += bf2f(v.z >> 16);
        a6 += bf2f(v.w & 0xffff);
        a7 += bf2f(v.w >> 16);
    }
    // combine quarters: xor 16, then xor 32
    a0 += __shfl_xor(a0, 16); a0 += __shfl_xor(a0, 32);
    a1 += __shfl_xor(a1, 16); a1 += __shfl_xor(a1, 32);
    a2 += __shfl_xor(a2, 16); a2 += __shfl_xor(a2, 32);
    a3 += __shfl_xor(a3, 16); a3 += __shfl_xor(a3, 32);
    a4 += __shfl_xor(a4, 16); a4 += __shfl_xor(a4, 32);
    a5 += __shfl_xor(a5, 16); a5 += __shfl_xor(a5, 32);
    a6 += __shfl_xor(a6, 16); a6 += __shfl_xor(a6, 32);
    a7 += __shfl_xor(a7, 16); a7 += __shfl_xor(a7, 32);
    if (q == 0) {
        float inv = 1.0f / fmaxf((float)d, 1.0f);
        uint4 o;
        o.x = ((unsigned int)f2bf(a1 * inv) << 16) | f2bf(a0 * inv);
        o.y = ((unsigned int)f2bf(a3 * inv) << 16) | f2bf(a2 * inv);
        o.z = ((unsigned int)f2bf(a5 * inv) << 16) | f2bf(a4 * inv);
        o.w = ((unsigned int)f2bf(a7 * inv) << 16) | f2bf(a6 * inv);
        *(uint4*)(aggb + (size_t)n * F + l4 * 8) = o;
    }
}

// ---------------- MFMA layer: out = [agg|x] @ Wpack + bl (+relu) ----------------
// 512 threads = 8 waves/block; W staged once in 64KB LDS, shared by all waves.
// A-frags prefetched to registers BEFORE the staging barrier (latency overlap).
__global__ __launch_bounds__(512) void sage_mfma(
    const unsigned short* __restrict__ aggb, const unsigned short* __restrict__ xb,
    const unsigned short* __restrict__ Wpack, const float* __restrict__ bl,
    unsigned short* __restrict__ outb, float* __restrict__ outf,
    int N, int final_layer) {
    __shared__ unsigned short sW[32768];  // 64 KB

    const int wid = threadIdx.x >> 6;
    const int lane = threadIdx.x & 63;
    const int row0 = (blockIdx.x * 8 + wid) * 16;
    const bool active = (row0 < N);

    // prefetch A fragments (global) before LDS staging so the latency overlaps
    short8v a[8];
    if (active) {
        const int rA = row0 + (lane & 15);
        const int kidx = (lane >> 4) << 3;  // 0,8,16,24
        const unsigned short* arow_a = aggb + (size_t)rA * F + kidx;
        const unsigned short* arow_x = xb + (size_t)rA * F + kidx;
#pragma unroll
        for (int kt = 0; kt < 4; ++kt) a[kt] = *(const short8v*)(arow_a + kt * 32);
#pragma unroll
        for (int kt = 4; kt < 8; ++kt) a[kt] = *(const short8v*)(arow_x + (kt - 4) * 32);
    }

    {
        const uint4* srcv = (const uint4*)Wpack;
        uint4* dstv = (uint4*)sW;
#pragma unroll
        for (int t = 0; t < 8; ++t)
            dstv[threadIdx.x + t * 512] = srcv[threadIdx.x + t * 512];
    }
    __syncthreads();
    if (!active) return;

    f32x4 acc[8];
#pragma unroll
    for (int nt = 0; nt < 8; ++nt) acc[nt] = (f32x4){0.f, 0.f, 0.f, 0.f};

#pragma unroll
    for (int kt = 0; kt < 8; ++kt) {
#pragma unroll
        for (int nt = 0; nt < 8; ++nt) {
            short8v b = *(const short8v*)(sW + ((kt * 8 + nt) * 64 + lane) * 8);
            acc[nt] = __builtin_amdgcn_mfma_f32_16x16x32_bf16(a[kt], b, acc[nt], 0, 0, 0);
        }
    }

    // C/D layout: col = lane&15, row = (lane>>4)*4 + reg   [m89-verified]
    const int c0 = lane & 15;
    const int r0 = row0 + ((lane >> 4) << 2);
#pragma unroll
    for (int nt = 0; nt < 8; ++nt) {
        const int col = nt * 16 + c0;
        const float b = bl[col];
#pragma unroll
        for (int reg = 0; reg < 4; ++reg) {
            const int r = r0 + reg;
            float v = acc[nt][reg] + b;
            if (!final_layer) {
                v = fmaxf(v, 0.f);
                outb[(size_t)r * F + col] = f2bf(v);
            } else {
                outf[(size_t)r * F + col] = v;
            }
        }
    }
}

extern "C" void kernel_launch(void* const* d_in, const int* in_sizes, int n_in,
                              void* d_out, int out_size, void* d_ws, size_t ws_size,
                              hipStream_t stream) {
    const float* x = (const float*)d_in[0];
    const int* ei = (const int*)d_in[1];
    const int E = in_sizes[1] / 2;
    const int N = in_sizes[0] / F;
    const int NCH = (N + 1023) / 1024;  // must be <= 64

    const float* Wl[3] = {(const float*)d_in[2], (const float*)d_in[5], (const float*)d_in[8]};
    const float* bl[3] = {(const float*)d_in[3], (const float*)d_in[6], (const float*)d_in[9]};
    const float* Wr[3] = {(const float*)d_in[4], (const float*)d_in[7], (const float*)d_in[10]};
    float* out = (float*)d_out;

    char* ws = (char*)d_ws;
    size_t off = 0;
    auto alloc = [&](size_t bytes) {
        size_t o = off;
        off = (off + bytes + 255) & ~(size_t)255;
        return o;
    };
    int* flag = (int*)(ws + alloc(4));
    int* deg = (int*)(ws + alloc((size_t)N * 4));
    int* rs = (int*)(ws + alloc((size_t)N * 4));
    int* partials = (int*)(ws + alloc(64 * 4));
    int* coff = (int*)(ws + alloc(64 * 4));
    int* rank = (int*)(ws + alloc((size_t)E * 4));
    int* adj = (int*)(ws + alloc((size_t)E * 4));
    unsigned short* xb = (unsigned short*)(ws + alloc((size_t)N * F * 2));
    unsigned short* aggb = (unsigned short*)(ws + alloc((size_t)N * F * 2));
    unsigned short* h1b = (unsigned short*)(ws + alloc((size_t)N * F * 2));
    unsigned short* h2b = (unsigned short*)(ws + alloc((size_t)N * F * 2));
    unsigned short* Wp = (unsigned short*)(ws + alloc((size_t)3 * 4096 * 8 * 2));

    // ---- prep: deg zero + flag + x->bf16 + W pack ----
    int ndegb = (N + 255) / 256;
    int nxb = (N * F / 4 + 255) / 256;
    prep<<<ndegb + nxb + 48, 256, 0, stream>>>(ei, flag, deg, N, x, xb, ndegb, nxb,
                                               Wl[0], Wr[0], Wl[1], Wr[1], Wl[2], Wr[2], Wp);

    // ---- CSR build ----
    count_rank<<<(E + 255) / 256, 256, 0, stream>>>(ei, flag, deg, rank, E);
    scan_local<<<NCH, 1024, 0, stream>>>(deg, rs, partials, N);
    scan_part<<<1, 64, 0, stream>>>(partials, coff, NCH);
    fill_adj<<<(E + 255) / 256, 256, 0, stream>>>(ei, flag, rs, coff, rank, adj, E);

    // ---- layers ----
    const unsigned short* cur = xb;
    unsigned short* hb[3] = {h1b, h2b, nullptr};
    int nwaves = (N + 15) / 16;
    int nblocks_m = (nwaves + 7) / 8;
    for (int layer = 0; layer < 3; ++layer) {
        gather_mean<<<(N * 64 + 255) / 256, 256, 0, stream>>>(cur, adj, rs, coff, deg, aggb, N);
        sage_mfma<<<nblocks_m, 512, 0, stream>>>(aggb, cur, Wp + (size_t)layer * 32768,
                                                 bl[layer], hb[layer], out, N, layer == 2);
        cur = hb[layer];
    }
}